// Round 6
// baseline (287.867 us; speedup 1.0000x reference)
//
#include <hip/hip_runtime.h>
#include <cstdint>
#include <cstddef>

#define DD 64

typedef float    f32x4  __attribute__((ext_vector_type(4)));
typedef float    f32x2  __attribute__((ext_vector_type(2)));
typedef _Float16 f16x8  __attribute__((ext_vector_type(8)));
typedef _Float16 f16x4  __attribute__((ext_vector_type(4)));

__device__ __forceinline__ float sigmoidf_(float x) {
    return 1.0f / (1.0f + __expf(-x));
}
__device__ __forceinline__ float tanh_fast(float x) {
    float ax = fabsf(x);
    float t = 1.0f - 2.0f / (1.0f + __expf(2.0f * ax));
    return copysignf(t, x);
}
__device__ __forceinline__ f32x4 MFMA(f32x4 c, f16x8 a, f16x8 b) {
    return __builtin_amdgcn_mfma_f32_16x16x32_f16(a, b, c, 0, 0, 0);
}

// ---------------- winner voting (winner[] lives in out2 region) ----------------
__global__ void k_init(int* __restrict__ winner, int num_nodes) {
    int i = blockIdx.x * blockDim.x + threadIdx.x;
    if (i < num_nodes) winner[i] = -1;
}
__global__ void k_vote(const int* __restrict__ ids, int* __restrict__ winner, int n) {
    int i = blockIdx.x * blockDim.x + threadIdx.x;
    if (i < n) atomicMax(&winner[ids[i]], i);
}

// ---------------- per-event precompute: {dt, id | win<<31} ----------------
// Decouples the random lut/winner gathers from k_gru (524K independent threads
// saturate HBM latency; k_gru then streams this coalesced).
__global__ void k_dt(const int* __restrict__ ids, const float* __restrict__ ts,
                     const float* __restrict__ lut, const int* __restrict__ winner,
                     f32x2* __restrict__ dtw, int n) {
    int ev = blockIdx.x * blockDim.x + threadIdx.x;
    if (ev < n) {
        int id = ids[ev];
        float dt = ts[ev] - lut[id];
        unsigned iw = (unsigned)id | ((winner[id] == ev) ? 0x80000000u : 0u);
        f32x2 v; v.x = dt; v.y = __uint_as_float(iw);
        dtw[ev] = v;
    }
}

// ---------------- build B fragments (hi/lo split fp16) into ws ----------------
__global__ void k_prep(const float* __restrict__ Wih, const float* __restrict__ Whh,
                       _Float16* __restrict__ bhi, _Float16* __restrict__ blo)
{
    int f = blockIdx.x;        // 0..63
    int l = threadIdx.x;       // 0..63
    int g = f >> 2, s = f & 3;
    int c = g * 16 + (l & 15);
    int grp = c >> 6, d = c & 63;
    int kbase = s * 32 + (l >> 4) * 8;
    int row = (grp == 0) ? d : (grp == 1) ? 64 + d : 128 + d;

    f16x8 hv, lv;
    for (int j = 0; j < 8; ++j) {
        int k = kbase + j;
        float v;
        if (grp <= 1)      v = (k < 64) ? Wih[row * 64 + k] : Whh[row * 64 + (k - 64)];
        else if (grp == 2) v = (k < 64) ? Wih[row * 64 + k] : 0.0f;
        else               v = (k < 64) ? 0.0f : Whh[row * 64 + (k - 64)];
        _Float16 h = (_Float16)v;
        hv[j] = h;
        lv[j] = (_Float16)(v - (float)h);
    }
    size_t off = ((size_t)f * 64 + l);
    ((f16x8*)bhi)[off] = hv;
    ((f16x8*)blo)[off] = lv;
}

// ---------------- main GRU kernel (MFMA, asymmetric split-fp16) ----------------
// One 64-event chunk per block; x split hi/lo, h plain fp16.
template<bool PRE>
__global__ __launch_bounds__(256, 4) void k_gru(
    const int* __restrict__ ids,
    const float* __restrict__ emb,
    const float* __restrict__ ts,
    const float* __restrict__ mem,
    const float* __restrict__ lut,
    const float* __restrict__ Wt,
    const float* __restrict__ bt,
    const float* __restrict__ bih,
    const float* __restrict__ bhh,
    const _Float16* __restrict__ bhi,
    const _Float16* __restrict__ blo,
    const int* __restrict__ winner,
    const f32x2* __restrict__ dtw,
    float* __restrict__ out0,
    float* __restrict__ out1,
    int n)
{
    __shared__ _Float16 xhh[64][136];   // hi plane: [event][k], k<64 x_hi, k>=64 h
    __shared__ _Float16 xhl[64][72];    // lo plane: x_lo only (k<64)
    __shared__ int sid[64];
    __shared__ int swin[64];

    const int w    = threadIdx.x >> 6;
    const int l    = threadIdx.x & 63;
    const int col  = l & 15;
    const int rowg = l >> 4;
    const int d    = w * 16 + col;      // output dim this lane owns in epilogue

    const float bR  = bih[d] + bhh[d];
    const float bZ  = bih[64 + d] + bhh[64 + d];
    const float bIN = bih[128 + d];
    const float bHN = bhh[128 + d];

    // persistent B fragments for this wave's 4 gate tiles (L2-resident)
    const f16x8* H = (const f16x8*)bhi;
    const f16x8* L = (const f16x8*)blo;
    f16x8 BRh0 = H[(size_t)(w * 4 + 0) * 64 + l];
    f16x8 BRh1 = H[(size_t)(w * 4 + 1) * 64 + l];
    f16x8 BRh2 = H[(size_t)(w * 4 + 2) * 64 + l];
    f16x8 BRh3 = H[(size_t)(w * 4 + 3) * 64 + l];
    f16x8 BRl0 = L[(size_t)(w * 4 + 0) * 64 + l];
    f16x8 BRl1 = L[(size_t)(w * 4 + 1) * 64 + l];
    f16x8 BZh0 = H[(size_t)((4 + w) * 4 + 0) * 64 + l];
    f16x8 BZh1 = H[(size_t)((4 + w) * 4 + 1) * 64 + l];
    f16x8 BZh2 = H[(size_t)((4 + w) * 4 + 2) * 64 + l];
    f16x8 BZh3 = H[(size_t)((4 + w) * 4 + 3) * 64 + l];
    f16x8 BZl0 = L[(size_t)((4 + w) * 4 + 0) * 64 + l];
    f16x8 BZl1 = L[(size_t)((4 + w) * 4 + 1) * 64 + l];
    f16x8 BIh0 = H[(size_t)((8 + w) * 4 + 0) * 64 + l];
    f16x8 BIh1 = H[(size_t)((8 + w) * 4 + 1) * 64 + l];
    f16x8 BIl0 = L[(size_t)((8 + w) * 4 + 0) * 64 + l];
    f16x8 BIl1 = L[(size_t)((8 + w) * 4 + 1) * 64 + l];
    f16x8 BHh0 = H[(size_t)((12 + w) * 4 + 2) * 64 + l];
    f16x8 BHh1 = H[(size_t)((12 + w) * 4 + 3) * 64 + l];

    const f32x4 wt4 = ((const f32x4*)Wt)[col];
    const f32x4 bt4 = ((const f32x4*)bt)[col];

    const long base = (long)blockIdx.x * 64;

    // ---- phase A: lanes 0..15 fetch per-event scalars (coalesced if PRE) ----
    float dtA = 0.f; int idA = 0;
    if (l < 16) {
        long ev = base + w * 16 + l;
        int id = 0, win = 0; float dt = 0.f;
        if (ev < n) {
            if (PRE) {
                f32x2 v = dtw[ev];
                dt = v.x;
                unsigned iw = __float_as_uint(v.y);
                id  = (int)(iw & 0x7FFFFFFFu);
                win = (int)(iw >> 31);
            } else {
                id = ids[ev];
                dt = ts[ev] - lut[id];
                win = (winner[id] == (int)ev) ? 1 : 0;
            }
        }
        idA = id; dtA = dt;
        sid[w * 16 + l] = id;
        swin[w * 16 + l] = win;
    }

    // ---- phase B: 4 iterations of 16B loads; each lane does 4 dims of 1 event ----
    #pragma unroll
    for (int it = 0; it < 4; ++it) {
        int  e_loc = it * 4 + rowg;           // 0..15
        int  r     = w * 16 + e_loc;
        long ev    = base + r;
        int   id = __shfl(idA, e_loc);
        float dt = __shfl(dtA, e_loc);
        f32x4 xv = {0.f, 0.f, 0.f, 0.f};
        f32x4 hv = {0.f, 0.f, 0.f, 0.f};
        if (ev < n) {
            xv = __builtin_nontemporal_load(&((const f32x4*)emb)[(size_t)ev * 16 + col]);
            hv = ((const f32x4*)mem)[(size_t)id * 16 + col];
            xv.x = fmaf(dt, wt4.x, xv.x + bt4.x);
            xv.y = fmaf(dt, wt4.y, xv.y + bt4.y);
            xv.z = fmaf(dt, wt4.z, xv.z + bt4.z);
            xv.w = fmaf(dt, wt4.w, xv.w + bt4.w);
        }
        f16x4 xh, xl, hh;
        {
            _Float16 a;
            a = (_Float16)xv.x; xh[0] = a; xl[0] = (_Float16)(xv.x - (float)a);
            a = (_Float16)xv.y; xh[1] = a; xl[1] = (_Float16)(xv.y - (float)a);
            a = (_Float16)xv.z; xh[2] = a; xl[2] = (_Float16)(xv.z - (float)a);
            a = (_Float16)xv.w; xh[3] = a; xl[3] = (_Float16)(xv.w - (float)a);
            hh[0] = (_Float16)hv.x;
            hh[1] = (_Float16)hv.y;
            hh[2] = (_Float16)hv.z;
            hh[3] = (_Float16)hv.w;
        }
        *(f16x4*)&xhh[r][col * 4]      = xh;
        *(f16x4*)&xhl[r][col * 4]      = xl;
        *(f16x4*)&xhh[r][64 + col * 4] = hh;
    }
    __syncthreads();

    // ---- 4 M-tiles of 16 events each ----
    #pragma unroll
    for (int mt = 0; mt < 4; ++mt) {
        const int arow = mt * 16 + col;
        const int k0   = rowg * 8;
        f16x8 Ah0 = *(const f16x8*)&xhh[arow][0 * 32 + k0];
        f16x8 Ah1 = *(const f16x8*)&xhh[arow][1 * 32 + k0];
        f16x8 Ah2 = *(const f16x8*)&xhh[arow][2 * 32 + k0];
        f16x8 Ah3 = *(const f16x8*)&xhh[arow][3 * 32 + k0];
        f16x8 Al0 = *(const f16x8*)&xhl[arow][0 * 32 + k0];
        f16x8 Al1 = *(const f16x8*)&xhl[arow][1 * 32 + k0];

        f32x4 aR = {0,0,0,0}, aZ = {0,0,0,0}, aI = {0,0,0,0}, aH = {0,0,0,0};
        __builtin_amdgcn_s_setprio(1);
        // r-gate: x part (s=0,1) 3-term, h part (s=2,3) 1-term
        aR = MFMA(aR, Ah0, BRh0); aR = MFMA(aR, Ah0, BRl0); aR = MFMA(aR, Al0, BRh0);
        aR = MFMA(aR, Ah1, BRh1); aR = MFMA(aR, Ah1, BRl1); aR = MFMA(aR, Al1, BRh1);
        aR = MFMA(aR, Ah2, BRh2); aR = MFMA(aR, Ah3, BRh3);
        // z-gate
        aZ = MFMA(aZ, Ah0, BZh0); aZ = MFMA(aZ, Ah0, BZl0); aZ = MFMA(aZ, Al0, BZh0);
        aZ = MFMA(aZ, Ah1, BZh1); aZ = MFMA(aZ, Ah1, BZl1); aZ = MFMA(aZ, Al1, BZh1);
        aZ = MFMA(aZ, Ah2, BZh2); aZ = MFMA(aZ, Ah3, BZh3);
        // i_n: x only
        aI = MFMA(aI, Ah0, BIh0); aI = MFMA(aI, Ah0, BIl0); aI = MFMA(aI, Al0, BIh0);
        aI = MFMA(aI, Ah1, BIh1); aI = MFMA(aI, Ah1, BIl1); aI = MFMA(aI, Al1, BIh1);
        // h_n: h only
        aH = MFMA(aH, Ah2, BHh0); aH = MFMA(aH, Ah3, BHh1);
        __builtin_amdgcn_s_setprio(0);

        // ---- epilogue: gates, output, fused winner scatter ----
        #pragma unroll
        for (int r = 0; r < 4; ++r) {
            int  eloc = mt * 16 + rowg * 4 + r;
            long ev   = base + eloc;
            if (ev < n) {
                float rr = sigmoidf_(aR[r] + bR);
                float zz = sigmoidf_(aZ[r] + bZ);
                float nn = tanh_fast(aI[r] + bIN + rr * (aH[r] + bHN));
                float hv = (float)xhh[eloc][64 + d];
                float o  = (1.f - zz) * nn + zz * hv;
                __builtin_nontemporal_store(o, &out0[(size_t)ev * 64 + d]);
                if (swin[eloc])
                    __builtin_nontemporal_store(o, &out1[(size_t)sid[eloc] * 64 + d]);
            }
        }
    }
}

// ---------------- fused tail: loser-row copy + timestamp scatter ----------------
// winner stored IN out2; each 16-thread group reads its node's winner, then lane
// c==0 overwrites that same slot (read-before-write within the wave -> safe).
__global__ void k_tail(float* out2,
                       const f32x4* __restrict__ mem4,
                       f32x4* __restrict__ out14,
                       const float* __restrict__ ts,
                       const float* __restrict__ lut,
                       int num_nodes)
{
    int idx = blockIdx.x * blockDim.x + threadIdx.x;
    if (idx >= num_nodes * 16) return;
    int nidx = idx >> 4;
    int c    = idx & 15;
    int wv = reinterpret_cast<const int*>(out2)[nidx];
    if (wv < 0) {
        f32x4 v = __builtin_nontemporal_load(&mem4[idx]);
        __builtin_nontemporal_store(v, &out14[idx]);
    }
    if (c == 0) out2[nidx] = (wv >= 0) ? ts[wv] : lut[nidx];
}

extern "C" void kernel_launch(void* const* d_in, const int* in_sizes, int n_in,
                              void* d_out, int out_size, void* d_ws, size_t ws_size,
                              hipStream_t stream) {
    const int*   ids = (const int*)  d_in[0];
    const float* emb = (const float*)d_in[1];
    const float* ts  = (const float*)d_in[2];
    const float* mem = (const float*)d_in[3];
    const float* lut = (const float*)d_in[4];
    const float* Wt  = (const float*)d_in[5];
    const float* bt  = (const float*)d_in[6];
    const float* Wih = (const float*)d_in[7];
    const float* Whh = (const float*)d_in[8];
    const float* bih = (const float*)d_in[9];
    const float* bhh = (const float*)d_in[10];

    const int N         = in_sizes[0];
    const int NUM_NODES = in_sizes[4];

    float* out0 = (float*)d_out;                    // [N,64]
    float* out1 = out0 + (size_t)N * DD;            // [NUM_NODES,64]
    float* out2 = out1 + (size_t)NUM_NODES * DD;    // [NUM_NODES]
    int*   winner = (int*)out2;

    _Float16* bfragH = (_Float16*)d_ws;                         // 64 KB
    _Float16* bfragL = bfragH + 64 * 64 * 8;                    // 64 KB
    f32x2*    dtw    = (f32x2*)((char*)d_ws + 128 * 1024);      // N * 8 B

    const size_t need = 128 * 1024 + (size_t)N * 8;
    const bool   pre  = (ws_size >= need);

    k_prep<<<64, 64, 0, stream>>>(Wih, Whh, bfragH, bfragL);
    k_init<<<(NUM_NODES + 255) / 256, 256, 0, stream>>>(winner, NUM_NODES);
    k_vote<<<(N + 255) / 256, 256, 0, stream>>>(ids, winner, N);

    int nchunks = (N + 63) / 64;
    if (pre) {
        k_dt<<<(N + 255) / 256, 256, 0, stream>>>(ids, ts, lut, winner, dtw, N);
        k_gru<true><<<nchunks, 256, 0, stream>>>(ids, emb, ts, mem, lut, Wt, bt,
                                                 bih, bhh, bfragH, bfragL, winner,
                                                 dtw, out0, out1, N);
    } else {
        k_gru<false><<<nchunks, 256, 0, stream>>>(ids, emb, ts, mem, lut, Wt, bt,
                                                  bih, bhh, bfragH, bfragL, winner,
                                                  dtw, out0, out1, N);
    }

    long vec = (long)NUM_NODES * 16;
    k_tail<<<(int)((vec + 255) / 256), 256, 0, stream>>>(
        out2, (const f32x4*)mem, (f32x4*)out1, ts, lut, NUM_NODES);
}

// Round 7
// 233.023 us; speedup vs baseline: 1.2354x; 1.2354x over previous
//
#include <hip/hip_runtime.h>
#include <cstdint>
#include <cstddef>

#define DD 64

typedef float    f32x4  __attribute__((ext_vector_type(4)));
typedef _Float16 f16x8  __attribute__((ext_vector_type(8)));
typedef _Float16 f16x4  __attribute__((ext_vector_type(4)));

__device__ __forceinline__ float sigmoidf_(float x) {
    return 1.0f / (1.0f + __expf(-x));
}
__device__ __forceinline__ float tanh_fast(float x) {
    float ax = fabsf(x);
    float t = 1.0f - 2.0f / (1.0f + __expf(2.0f * ax));
    return copysignf(t, x);
}
__device__ __forceinline__ f32x4 MFMA(f32x4 c, f16x8 a, f16x8 b) {
    return __builtin_amdgcn_mfma_f32_16x16x32_f16(a, b, c, 0, 0, 0);
}

// ---------------- winner voting (winner[] lives in out2 region) ----------------
__global__ void k_init(int* __restrict__ winner, int num_nodes) {
    int i = blockIdx.x * blockDim.x + threadIdx.x;
    if (i < num_nodes) winner[i] = -1;
}
__global__ void k_vote(const int* __restrict__ ids, int* __restrict__ winner, int n) {
    int i = blockIdx.x * blockDim.x + threadIdx.x;
    if (i < n) atomicMax(&winner[ids[i]], i);
}

// ---------------- build B fragments (hi/lo split fp16) into ws ----------------
// Conceptual B[128][256]: cols 0..63 r-gate (K: x then h), 64..127 z-gate,
// 128..191 i_n (x only), 192..255 h_n (h only).
// Fragment f = g*4+s (g=tile 0..15, s=K-step 0..3); lane l holds
// B[s*32+(l>>4)*8+j][g*16+(l&15)], j=0..7, packed 8 fp16 = 16B.
__global__ void k_prep(const float* __restrict__ Wih, const float* __restrict__ Whh,
                       _Float16* __restrict__ bhi, _Float16* __restrict__ blo)
{
    int f = blockIdx.x;        // 0..63
    int l = threadIdx.x;       // 0..63
    int g = f >> 2, s = f & 3;
    int c = g * 16 + (l & 15);
    int grp = c >> 6, d = c & 63;
    int kbase = s * 32 + (l >> 4) * 8;
    int row = (grp == 0) ? d : (grp == 1) ? 64 + d : 128 + d;

    f16x8 hv, lv;
    for (int j = 0; j < 8; ++j) {
        int k = kbase + j;
        float v;
        if (grp <= 1)      v = (k < 64) ? Wih[row * 64 + k] : Whh[row * 64 + (k - 64)];
        else if (grp == 2) v = (k < 64) ? Wih[row * 64 + k] : 0.0f;
        else               v = (k < 64) ? 0.0f : Whh[row * 64 + (k - 64)];
        _Float16 h = (_Float16)v;
        hv[j] = h;
        lv[j] = (_Float16)(v - (float)h);
    }
    size_t off = ((size_t)f * 64 + l);
    ((f16x8*)bhi)[off] = hv;
    ((f16x8*)blo)[off] = lv;
}

// ---------------- main GRU kernel (MFMA, asymmetric split-fp16) ----------------
// One 64-event chunk per block; x split hi/lo, h plain fp16.
// Phase A branch-free (4x redundant scalar gathers share cache lines);
// Phase B = T14 split: issue all 8x16B loads, then convert+LDS-write.
__global__ __launch_bounds__(256, 3) void k_gru(
    const int* __restrict__ ids,
    const float* __restrict__ emb,
    const float* __restrict__ ts,
    const float* __restrict__ mem,
    const float* __restrict__ lut,
    const float* __restrict__ Wt,
    const float* __restrict__ bt,
    const float* __restrict__ bih,
    const float* __restrict__ bhh,
    const _Float16* __restrict__ bhi,
    const _Float16* __restrict__ blo,
    const int* __restrict__ winner,
    float* __restrict__ out0,
    float* __restrict__ out1,
    int n)
{
    __shared__ _Float16 xhh[64][136];   // hi plane: [event][k], k<64 x_hi, k>=64 h
    __shared__ _Float16 xhl[64][72];    // lo plane: x_lo only (k<64)
    __shared__ int sid[64];
    __shared__ int swin[64];

    const int w    = threadIdx.x >> 6;
    const int l    = threadIdx.x & 63;
    const int col  = l & 15;
    const int rowg = l >> 4;
    const int d    = w * 16 + col;      // output dim this lane owns in epilogue

    const long base = (long)blockIdx.x * 64;
    const bool full = (base + 64 <= (long)n);

    // ---- phase A: every lane loads its event's scalars (lanes mod 16 alias) ----
    const int  e16 = w * 16 + col;
    const long evA = base + e16;
    int idA = 0, winA = 0; float dtA = 0.f;
    if (full || evA < n) {
        idA  = ids[evA];
        dtA  = ts[evA] - lut[idA];
        winA = (winner[idA] == (int)evA) ? 1 : 0;
    }
    if (l < 16) { sid[e16] = idA; swin[e16] = winA; }

    // ---- phase B load pass: issue all 8 global 16B loads back-to-back ----
    f32x4 xv0, xv1, xv2, xv3, hv0, hv1, hv2, hv3;
    float dt0, dt1, dt2, dt3;
    {
        int   i0 = __shfl(idA, 0 * 4 + rowg), i1 = __shfl(idA, 1 * 4 + rowg);
        int   i2 = __shfl(idA, 2 * 4 + rowg), i3 = __shfl(idA, 3 * 4 + rowg);
        dt0 = __shfl(dtA, 0 * 4 + rowg); dt1 = __shfl(dtA, 1 * 4 + rowg);
        dt2 = __shfl(dtA, 2 * 4 + rowg); dt3 = __shfl(dtA, 3 * 4 + rowg);
        const f32x4* emb4 = (const f32x4*)emb;
        const f32x4* mem4 = (const f32x4*)mem;
        const size_t e0 = (size_t)(base + w * 16 + 0 * 4 + rowg) * 16 + col;
        const size_t e1 = (size_t)(base + w * 16 + 1 * 4 + rowg) * 16 + col;
        const size_t e2 = (size_t)(base + w * 16 + 2 * 4 + rowg) * 16 + col;
        const size_t e3 = (size_t)(base + w * 16 + 3 * 4 + rowg) * 16 + col;
        if (full) {
            xv0 = __builtin_nontemporal_load(&emb4[e0]);
            xv1 = __builtin_nontemporal_load(&emb4[e1]);
            xv2 = __builtin_nontemporal_load(&emb4[e2]);
            xv3 = __builtin_nontemporal_load(&emb4[e3]);
            hv0 = mem4[(size_t)i0 * 16 + col];
            hv1 = mem4[(size_t)i1 * 16 + col];
            hv2 = mem4[(size_t)i2 * 16 + col];
            hv3 = mem4[(size_t)i3 * 16 + col];
        } else {
            f32x4 z = {0.f, 0.f, 0.f, 0.f};
            xv0 = xv1 = xv2 = xv3 = hv0 = hv1 = hv2 = hv3 = z;
            if (base + w * 16 + 0 * 4 + rowg < n) { xv0 = emb4[e0]; hv0 = mem4[(size_t)i0 * 16 + col]; }
            if (base + w * 16 + 1 * 4 + rowg < n) { xv1 = emb4[e1]; hv1 = mem4[(size_t)i1 * 16 + col]; }
            if (base + w * 16 + 2 * 4 + rowg < n) { xv2 = emb4[e2]; hv2 = mem4[(size_t)i2 * 16 + col]; }
            if (base + w * 16 + 3 * 4 + rowg < n) { xv3 = emb4[e3]; hv3 = mem4[(size_t)i3 * 16 + col]; }
        }
    }

    // ---- phase B convert/write pass ----
    const f32x4 wt4 = ((const f32x4*)Wt)[col];
    const f32x4 bt4 = ((const f32x4*)bt)[col];
    {
        #define CONV_WRITE(XV, HV, DT, IT)                                           \
        {                                                                            \
            int r = w * 16 + (IT) * 4 + rowg;                                        \
            f32x4 x = XV;                                                            \
            x.x = fmaf(DT, wt4.x, x.x + bt4.x);                                      \
            x.y = fmaf(DT, wt4.y, x.y + bt4.y);                                      \
            x.z = fmaf(DT, wt4.z, x.z + bt4.z);                                      \
            x.w = fmaf(DT, wt4.w, x.w + bt4.w);                                      \
            f16x4 xh, xl, hh;                                                        \
            _Float16 a;                                                              \
            a = (_Float16)x.x; xh[0] = a; xl[0] = (_Float16)(x.x - (float)a);        \
            a = (_Float16)x.y; xh[1] = a; xl[1] = (_Float16)(x.y - (float)a);        \
            a = (_Float16)x.z; xh[2] = a; xl[2] = (_Float16)(x.z - (float)a);        \
            a = (_Float16)x.w; xh[3] = a; xl[3] = (_Float16)(x.w - (float)a);        \
            hh[0] = (_Float16)(HV).x; hh[1] = (_Float16)(HV).y;                      \
            hh[2] = (_Float16)(HV).z; hh[3] = (_Float16)(HV).w;                      \
            *(f16x4*)&xhh[r][col * 4]      = xh;                                     \
            *(f16x4*)&xhl[r][col * 4]      = xl;                                     \
            *(f16x4*)&xhh[r][64 + col * 4] = hh;                                     \
        }
        CONV_WRITE(xv0, hv0, dt0, 0)
        CONV_WRITE(xv1, hv1, dt1, 1)
        CONV_WRITE(xv2, hv2, dt2, 2)
        CONV_WRITE(xv3, hv3, dt3, 3)
        #undef CONV_WRITE
    }

    // persistent B fragments for this wave's 4 gate tiles (L2-resident)
    const f16x8* H = (const f16x8*)bhi;
    const f16x8* L = (const f16x8*)blo;
    f16x8 BRh0 = H[(size_t)(w * 4 + 0) * 64 + l];
    f16x8 BRh1 = H[(size_t)(w * 4 + 1) * 64 + l];
    f16x8 BRh2 = H[(size_t)(w * 4 + 2) * 64 + l];
    f16x8 BRh3 = H[(size_t)(w * 4 + 3) * 64 + l];
    f16x8 BRl0 = L[(size_t)(w * 4 + 0) * 64 + l];
    f16x8 BRl1 = L[(size_t)(w * 4 + 1) * 64 + l];
    f16x8 BZh0 = H[(size_t)((4 + w) * 4 + 0) * 64 + l];
    f16x8 BZh1 = H[(size_t)((4 + w) * 4 + 1) * 64 + l];
    f16x8 BZh2 = H[(size_t)((4 + w) * 4 + 2) * 64 + l];
    f16x8 BZh3 = H[(size_t)((4 + w) * 4 + 3) * 64 + l];
    f16x8 BZl0 = L[(size_t)((4 + w) * 4 + 0) * 64 + l];
    f16x8 BZl1 = L[(size_t)((4 + w) * 4 + 1) * 64 + l];
    f16x8 BIh0 = H[(size_t)((8 + w) * 4 + 0) * 64 + l];
    f16x8 BIh1 = H[(size_t)((8 + w) * 4 + 1) * 64 + l];
    f16x8 BIl0 = L[(size_t)((8 + w) * 4 + 0) * 64 + l];
    f16x8 BIl1 = L[(size_t)((8 + w) * 4 + 1) * 64 + l];
    f16x8 BHh0 = H[(size_t)((12 + w) * 4 + 2) * 64 + l];
    f16x8 BHh1 = H[(size_t)((12 + w) * 4 + 3) * 64 + l];

    const float bR  = bih[d] + bhh[d];
    const float bZ  = bih[64 + d] + bhh[64 + d];
    const float bIN = bih[128 + d];
    const float bHN = bhh[128 + d];

    __syncthreads();

    // ---- 4 M-tiles of 16 events each ----
    #pragma unroll
    for (int mt = 0; mt < 4; ++mt) {
        const int arow = mt * 16 + col;
        const int k0   = rowg * 8;
        f16x8 Ah0 = *(const f16x8*)&xhh[arow][0 * 32 + k0];
        f16x8 Ah1 = *(const f16x8*)&xhh[arow][1 * 32 + k0];
        f16x8 Ah2 = *(const f16x8*)&xhh[arow][2 * 32 + k0];
        f16x8 Ah3 = *(const f16x8*)&xhh[arow][3 * 32 + k0];
        f16x8 Al0 = *(const f16x8*)&xhl[arow][0 * 32 + k0];
        f16x8 Al1 = *(const f16x8*)&xhl[arow][1 * 32 + k0];

        f32x4 aR = {0,0,0,0}, aZ = {0,0,0,0}, aI = {0,0,0,0}, aH = {0,0,0,0};
        __builtin_amdgcn_s_setprio(1);
        // r-gate: x part (s=0,1) 3-term, h part (s=2,3) 1-term
        aR = MFMA(aR, Ah0, BRh0); aR = MFMA(aR, Ah0, BRl0); aR = MFMA(aR, Al0, BRh0);
        aR = MFMA(aR, Ah1, BRh1); aR = MFMA(aR, Ah1, BRl1); aR = MFMA(aR, Al1, BRh1);
        aR = MFMA(aR, Ah2, BRh2); aR = MFMA(aR, Ah3, BRh3);
        // z-gate
        aZ = MFMA(aZ, Ah0, BZh0); aZ = MFMA(aZ, Ah0, BZl0); aZ = MFMA(aZ, Al0, BZh0);
        aZ = MFMA(aZ, Ah1, BZh1); aZ = MFMA(aZ, Ah1, BZl1); aZ = MFMA(aZ, Al1, BZh1);
        aZ = MFMA(aZ, Ah2, BZh2); aZ = MFMA(aZ, Ah3, BZh3);
        // i_n: x only
        aI = MFMA(aI, Ah0, BIh0); aI = MFMA(aI, Ah0, BIl0); aI = MFMA(aI, Al0, BIh0);
        aI = MFMA(aI, Ah1, BIh1); aI = MFMA(aI, Ah1, BIl1); aI = MFMA(aI, Al1, BIh1);
        // h_n: h only
        aH = MFMA(aH, Ah2, BHh0); aH = MFMA(aH, Ah3, BHh1);
        __builtin_amdgcn_s_setprio(0);

        // ---- epilogue: gates, output, fused winner scatter ----
        #pragma unroll
        for (int r = 0; r < 4; ++r) {
            int  eloc = mt * 16 + rowg * 4 + r;
            long ev   = base + eloc;
            if (full || ev < n) {
                float rr = sigmoidf_(aR[r] + bR);
                float zz = sigmoidf_(aZ[r] + bZ);
                float nn = tanh_fast(aI[r] + bIN + rr * (aH[r] + bHN));
                float hv = (float)xhh[eloc][64 + d];
                float o  = (1.f - zz) * nn + zz * hv;
                __builtin_nontemporal_store(o, &out0[(size_t)ev * 64 + d]);
                if (swin[eloc])
                    __builtin_nontemporal_store(o, &out1[(size_t)sid[eloc] * 64 + d]);
            }
        }
    }
}

// ---------------- fused tail: loser-row copy + timestamp scatter ----------------
// winner stored IN out2; each 16-thread group reads its node's winner, then lane
// c==0 overwrites that same slot (read-before-write within the wave -> safe).
__global__ void k_tail(float* out2,
                       const f32x4* __restrict__ mem4,
                       f32x4* __restrict__ out14,
                       const float* __restrict__ ts,
                       const float* __restrict__ lut,
                       int num_nodes)
{
    int idx = blockIdx.x * blockDim.x + threadIdx.x;
    if (idx >= num_nodes * 16) return;
    int nidx = idx >> 4;
    int c    = idx & 15;
    int wv = reinterpret_cast<const int*>(out2)[nidx];
    if (wv < 0) {
        f32x4 v = __builtin_nontemporal_load(&mem4[idx]);
        __builtin_nontemporal_store(v, &out14[idx]);
    }
    if (c == 0) out2[nidx] = (wv >= 0) ? ts[wv] : lut[nidx];
}

extern "C" void kernel_launch(void* const* d_in, const int* in_sizes, int n_in,
                              void* d_out, int out_size, void* d_ws, size_t ws_size,
                              hipStream_t stream) {
    const int*   ids = (const int*)  d_in[0];
    const float* emb = (const float*)d_in[1];
    const float* ts  = (const float*)d_in[2];
    const float* mem = (const float*)d_in[3];
    const float* lut = (const float*)d_in[4];
    const float* Wt  = (const float*)d_in[5];
    const float* bt  = (const float*)d_in[6];
    const float* Wih = (const float*)d_in[7];
    const float* Whh = (const float*)d_in[8];
    const float* bih = (const float*)d_in[9];
    const float* bhh = (const float*)d_in[10];

    const int N         = in_sizes[0];
    const int NUM_NODES = in_sizes[4];

    float* out0 = (float*)d_out;                    // [N,64]
    float* out1 = out0 + (size_t)N * DD;            // [NUM_NODES,64]
    float* out2 = out1 + (size_t)NUM_NODES * DD;    // [NUM_NODES]
    int*   winner = (int*)out2;

    _Float16* bfragH = (_Float16*)d_ws;             // 64 KB
    _Float16* bfragL = bfragH + 64 * 64 * 8;        // 64 KB

    k_prep<<<64, 64, 0, stream>>>(Wih, Whh, bfragH, bfragL);
    k_init<<<(NUM_NODES + 255) / 256, 256, 0, stream>>>(winner, NUM_NODES);
    k_vote<<<(N + 255) / 256, 256, 0, stream>>>(ids, winner, N);

    int nchunks = (N + 63) / 64;
    k_gru<<<nchunks, 256, 0, stream>>>(ids, emb, ts, mem, lut, Wt, bt, bih, bhh,
                                       bfragH, bfragL, winner, out0, out1, N);

    long vec = (long)NUM_NODES * 16;
    k_tail<<<(int)((vec + 255) / 256), 256, 0, stream>>>(
        out2, (const f32x4*)mem, (f32x4*)out1, ts, lut, NUM_NODES);
}